// Round 16
// baseline (100.973 us; speedup 1.0000x reference)
//
#include <hip/hip_runtime.h>
#include <hip/hip_fp16.h>

// ---------------------------------------------------------------------------
// Round-15: r14 skeleton (proven 100us) with two LDS diets.
//   memset(counts) ;
//   convhist (fp32->fp16 table conv + 391-bucket hist) ;
//   scan (1 block, shfl: bucket offsets; writes goff[NB], noff[N]) ;
//   bin (two-phase flush: stage+flush keys, re-stage ef in SAME 16KB buffer,
//        flush again -> LDS 28KB, 4 blocks/CU) ;
//   bsort (bucket window staged in LDS once: hist+place from LDS; node-sorted
//          4B srcs + per-node offsets; esum -> out[:,64]) ;
//   gather (r10-proven: 1 wave/node, 8-deep unroll, fp16 rows, linear store).
// Key: (dst & 255) << 17 | src   (needs N <= 2^17).
// ---------------------------------------------------------------------------

#define NB_SHIFT 8
#define BNODES   256          // nodes per bucket
#define SRC_BITS 17
#define SRC_MASK ((1 << SRC_BITS) - 1)
#define BIN_S    4096         // edges per bin/hist block
#define BIN_T    512
#define MAXNB    512
#define BS_CAP   3584         // bsort LDS window capacity (edges)

// Fused: blocks [0, c_blocks) convert the table fp32->fp16; the rest
// histogram dst into bucket counts (LDS-aggregated).
__global__ __launch_bounds__(BIN_T) void convhist_kernel(const float* __restrict__ g,
                                                         __half* __restrict__ h,
                                                         int n_emb, int c_blocks,
                                                         const int* __restrict__ dst,
                                                         int* __restrict__ counts,
                                                         int E, int NB) {
    __shared__ int cnt[MAXNB];
    int t = threadIdx.x;

    if (blockIdx.x < c_blocks) {
        int i = (blockIdx.x * BIN_T + t) * 8;
        if (i + 7 < n_emb) {
            float4 a = *(const float4*)(g + i);
            float4 b = *(const float4*)(g + i + 4);
            __half2 h0 = __floats2half2_rn(a.x, a.y);
            __half2 h1 = __floats2half2_rn(a.z, a.w);
            __half2 h2 = __floats2half2_rn(b.x, b.y);
            __half2 h3 = __floats2half2_rn(b.z, b.w);
            int4 o;
            o.x = *(int*)&h0; o.y = *(int*)&h1; o.z = *(int*)&h2; o.w = *(int*)&h3;
            *(int4*)(h + i) = o;
        } else {
            for (int k = i; k < n_emb; ++k) h[k] = __float2half(g[k]);
        }
        return;
    }

    int hb = blockIdx.x - c_blocks;
    cnt[t] = 0;
    __syncthreads();
    int e0 = hb * BIN_S + t * 8;
    if (e0 + 7 < E) {
        int4 a = *(const int4*)(dst + e0);
        int4 b = *(const int4*)(dst + e0 + 4);
        atomicAdd(&cnt[a.x >> NB_SHIFT], 1);
        atomicAdd(&cnt[a.y >> NB_SHIFT], 1);
        atomicAdd(&cnt[a.z >> NB_SHIFT], 1);
        atomicAdd(&cnt[a.w >> NB_SHIFT], 1);
        atomicAdd(&cnt[b.x >> NB_SHIFT], 1);
        atomicAdd(&cnt[b.y >> NB_SHIFT], 1);
        atomicAdd(&cnt[b.z >> NB_SHIFT], 1);
        atomicAdd(&cnt[b.w >> NB_SHIFT], 1);
    } else {
        for (int k = e0; k < E; ++k) atomicAdd(&cnt[dst[k] >> NB_SHIFT], 1);
    }
    __syncthreads();
    if (t < NB && cnt[t]) atomicAdd(&counts[t], cnt[t]);
}

// Exclusive scan over NB (<=512) counters; one block, 512 threads, shfl.
__global__ __launch_bounds__(512) void scan_kernel(const int* __restrict__ counts,
                                                   int* __restrict__ goff,
                                                   int* __restrict__ gcur,
                                                   int* __restrict__ noff,
                                                   int NB, int N) {
    __shared__ int wsum[8];
    __shared__ int wbase[8];
    int t    = threadIdx.x;
    int lane = t & 63;
    int wv   = t >> 6;
    int v    = (t < NB) ? counts[t] : 0;
    int incl = v;
#pragma unroll
    for (int o = 1; o < 64; o <<= 1) {
        int u = __shfl_up(incl, o);
        if (lane >= o) incl += u;
    }
    if (lane == 63) wsum[wv] = incl;
    __syncthreads();
    if (t < 8) {
        int s = wsum[t];
        int inc = s;
#pragma unroll
        for (int o = 1; o < 8; o <<= 1) {
            int u = __shfl_up(inc, o);
            if (t >= o) inc += u;
        }
        wbase[t] = inc - s;
    }
    __syncthreads();
    int ex = wbase[wv] + (incl - v);
    if (t < NB) { goff[t] = ex; gcur[t] = ex; }
    if (t == 511) {
        int total = wbase[7] + incl;   // counts above NB are zero
        goff[NB] = total;
        noff[N]  = total;
    }
}

// bin: local histogram+rank (512 counters, 1/thread), shfl scans; two-phase
// flush reusing ONE 16KB stage buffer (keys, then ef) -> LDS 28KB.
__global__ __launch_bounds__(BIN_T) void bin_kernel(const int* __restrict__ src,
                                                    const float* __restrict__ ef,
                                                    const int* __restrict__ dst,
                                                    int* __restrict__ gcur,
                                                    int* __restrict__ gkey,
                                                    float* __restrict__ gef, int E) {
    __shared__ int cnt[MAXNB];              // 2 KB
    __shared__ int lbase[MAXNB];            // 2 KB
    __shared__ int wsum[8];
    __shared__ int wbase[8];
    __shared__ int stage[BIN_S];            // 16 KB (keys, then ef bits)
    __shared__ unsigned short sbuck[BIN_S]; // 8 KB   (total ~28 KB)

    const int t    = threadIdx.x;
    const int lane = t & 63;
    const int wv   = t >> 6;

    cnt[t] = 0;
    __syncthreads();

    int e0 = blockIdx.x * BIN_S + t * 8;
    int dv[8], sv[8], bk[8], rk[8];
    float ev[8];

    if (e0 + 7 < E) {
        *(int4*)&dv[0]   = *(const int4*)(dst + e0);
        *(int4*)&dv[4]   = *(const int4*)(dst + e0 + 4);
        *(int4*)&sv[0]   = *(const int4*)(src + e0);
        *(int4*)&sv[4]   = *(const int4*)(src + e0 + 4);
        *(float4*)&ev[0] = *(const float4*)(ef + e0);
        *(float4*)&ev[4] = *(const float4*)(ef + e0 + 4);
#pragma unroll
        for (int k = 0; k < 8; ++k) {
            bk[k] = dv[k] >> NB_SHIFT;
            rk[k] = atomicAdd(&cnt[bk[k]], 1);
        }
    } else {
#pragma unroll
        for (int k = 0; k < 8; ++k) {
            if (e0 + k < E) {
                dv[k] = dst[e0 + k];
                sv[k] = src[e0 + k];
                ev[k] = ef[e0 + k];
                bk[k] = dv[k] >> NB_SHIFT;
                rk[k] = atomicAdd(&cnt[bk[k]], 1);
            } else {
                bk[k] = -1;
            }
        }
    }
    __syncthreads();

    // exclusive scan of cnt[0..511], 1/thread: wave shfl scan + cross-wave
    int c = cnt[t];
    int incl = c;
#pragma unroll
    for (int o = 1; o < 64; o <<= 1) {
        int u = __shfl_up(incl, o);
        if (lane >= o) incl += u;
    }
    if (lane == 63) wsum[wv] = incl;
    __syncthreads();
    if (t < 8) {
        int s = wsum[t];
        int inc = s;
#pragma unroll
        for (int o = 1; o < 8; o <<= 1) {
            int u = __shfl_up(inc, o);
            if (t >= o) inc += u;
        }
        wbase[t] = inc - s;
    }
    __syncthreads();
    int lb = wbase[wv] + (incl - c);
    lbase[t] = lb;
    __syncthreads();

    // phase 1: stage ranked keys (+bucket tags)
#pragma unroll
    for (int k = 0; k < 8; ++k) {
        if (bk[k] >= 0) {
            int pos = lbase[bk[k]] + rk[k];
            stage[pos] = ((dv[k] & (BNODES - 1)) << SRC_BITS) | sv[k];
            sbuck[pos] = (unsigned short)bk[k];
        }
    }
    // reserve; cnt[b] becomes (global_base - local_base)
    cnt[t] = (c ? atomicAdd(&gcur[t], c) : 0) - lb;
    __syncthreads();

    // flush keys (coalesced)
    int s_total = min(BIN_S, E - blockIdx.x * BIN_S);
    for (int i = t; i < s_total; i += BIN_T)
        gkey[cnt[sbuck[i]] + i] = stage[i];
    __syncthreads();

    // phase 2: re-stage ef into the SAME buffer, flush
#pragma unroll
    for (int k = 0; k < 8; ++k) {
        if (bk[k] >= 0)
            stage[lbase[bk[k]] + rk[k]] = __float_as_int(ev[k]);
    }
    __syncthreads();
    for (int i = t; i < s_total; i += BIN_T)
        gef[cnt[sbuck[i]] + i] = __int_as_float(stage[i]);
}

// Bucket-local counting sort, bucket window staged in LDS (<=BS_CAP edges;
// overflow handled from global). Emits node-sorted 4B srcs + per-node
// offsets; accumulates efeat per node in LDS and writes out[:,64].
__global__ __launch_bounds__(512) void bsort_kernel(const int* __restrict__ gkey,
                                                    const float* __restrict__ gef,
                                                    const int* __restrict__ goff,
                                                    int* __restrict__ gsrc2,
                                                    int* __restrict__ noff,
                                                    float* __restrict__ out,
                                                    int N) {
    __shared__ int   cnt[BNODES];
    __shared__ int   cur[BNODES];
    __shared__ float esum[BNODES];
    __shared__ int   wkey[BS_CAP];   // 14 KB
    __shared__ float wef[BS_CAP];    // 14 KB

    const int t  = threadIdx.x;
    const int b  = blockIdx.x;
    const int lo = goff[b];
    const int hi = goff[b + 1];
    const int csize  = hi - lo;
    const int staged = min(csize, BS_CAP);

    if (t < BNODES) { cnt[t] = 0; esum[t] = 0.f; }
    __syncthreads();

    // stage window + histogram in one pass
    for (int i = t; i < staged; i += 512) {
        int k   = gkey[lo + i];
        float e = gef[lo + i];
        wkey[i] = k;
        wef[i]  = e;
        atomicAdd(&cnt[k >> SRC_BITS], 1);
    }
    for (int i = BS_CAP + t; i < csize; i += 512)      // overflow (rare)
        atomicAdd(&cnt[gkey[lo + i] >> SRC_BITS], 1);
    __syncthreads();

    // wave-0 shfl exclusive scan of 256 counters (4/lane)
    if (t < 64) {
        int c0 = cnt[4 * t], c1 = cnt[4 * t + 1], c2 = cnt[4 * t + 2], c3 = cnt[4 * t + 3];
        int ts = c0 + c1 + c2 + c3;
        int inc = ts;
#pragma unroll
        for (int o = 1; o < 64; o <<= 1) {
            int u = __shfl_up(inc, o);
            if (t >= o) inc += u;
        }
        int ex = inc - ts;
        int b0 = lo + ex;
        int b1 = b0 + c0;
        int b2 = b1 + c1;
        int b3 = b2 + c2;
        cur[4 * t]     = b0;
        cur[4 * t + 1] = b1;
        cur[4 * t + 2] = b2;
        cur[4 * t + 3] = b3;
        int node = b * BNODES + 4 * t;
        if (node     < N) noff[node]     = b0;
        if (node + 1 < N) noff[node + 1] = b1;
        if (node + 2 < N) noff[node + 2] = b2;
        if (node + 3 < N) noff[node + 3] = b3;
    }
    __syncthreads();

    // place node-sorted srcs from LDS; accumulate efeat per node
    for (int i = t; i < staged; i += 512) {
        int k = wkey[i];
        int r = k >> SRC_BITS;
        int pos = atomicAdd(&cur[r], 1);
        gsrc2[pos] = k & SRC_MASK;
        atomicAdd(&esum[r], wef[i]);
    }
    for (int i = BS_CAP + t; i < csize; i += 512) {    // overflow (rare)
        int k = gkey[lo + i];
        int r = k >> SRC_BITS;
        int pos = atomicAdd(&cur[r], 1);
        gsrc2[pos] = k & SRC_MASK;
        atomicAdd(&esum[r], gef[lo + i]);
    }
    __syncthreads();

    // efeat column
    if (t < BNODES) {
        int node = b * BNODES + t;
        if (node < N) out[(size_t)node * 65 + 64] = esum[t];
    }
}

// Gather: one wave per node, lane = feature, fp16 rows, 8-way unroll.
__global__ void gather_h_kernel(const __half* __restrict__ hg,
                                const int* __restrict__ gs,
                                const int* __restrict__ noff,
                                float* __restrict__ out, int N) {
    int wid  = (blockIdx.x * blockDim.x + threadIdx.x) >> 6;
    int lane = threadIdx.x & 63;
    if (wid >= N) return;

    int beg = noff[wid];
    int end = noff[wid + 1];

    float a0 = 0.f, a1 = 0.f, a2 = 0.f, a3 = 0.f;
    float a4 = 0.f, a5 = 0.f, a6 = 0.f, a7 = 0.f;
    int j = beg;
    for (; j + 7 < end; j += 8) {
        int s0 = gs[j];     int s1 = gs[j + 1];
        int s2 = gs[j + 2]; int s3 = gs[j + 3];
        int s4 = gs[j + 4]; int s5 = gs[j + 5];
        int s6 = gs[j + 6]; int s7 = gs[j + 7];
        a0 += __half2float(hg[(size_t)s0 * 64 + lane]);
        a1 += __half2float(hg[(size_t)s1 * 64 + lane]);
        a2 += __half2float(hg[(size_t)s2 * 64 + lane]);
        a3 += __half2float(hg[(size_t)s3 * 64 + lane]);
        a4 += __half2float(hg[(size_t)s4 * 64 + lane]);
        a5 += __half2float(hg[(size_t)s5 * 64 + lane]);
        a6 += __half2float(hg[(size_t)s6 * 64 + lane]);
        a7 += __half2float(hg[(size_t)s7 * 64 + lane]);
    }
    for (; j + 3 < end; j += 4) {
        int s0 = gs[j];     int s1 = gs[j + 1];
        int s2 = gs[j + 2]; int s3 = gs[j + 3];
        a0 += __half2float(hg[(size_t)s0 * 64 + lane]);
        a1 += __half2float(hg[(size_t)s1 * 64 + lane]);
        a2 += __half2float(hg[(size_t)s2 * 64 + lane]);
        a3 += __half2float(hg[(size_t)s3 * 64 + lane]);
    }
    for (; j < end; ++j) {
        a0 += __half2float(hg[(size_t)gs[j] * 64 + lane]);
    }
    out[(size_t)wid * 65 + lane] = ((a0 + a1) + (a2 + a3)) + ((a4 + a5) + (a6 + a7));
}

// ---------------------- fallback (always correct) --------------------------

__global__ void atomic_fallback_kernel(const float* __restrict__ gemb,
                                       const float* __restrict__ efeat,
                                       const int* __restrict__ src,
                                       const int* __restrict__ dst,
                                       float* __restrict__ out, int E) {
    int eidx = blockIdx.x * 4 + (threadIdx.x >> 6);
    int lane = threadIdx.x & 63;
    if (eidx >= E) return;
    int s = src[eidx];
    int d = dst[eidx];
    float v = gemb[(size_t)s * 64 + lane];
    atomicAdd(&out[(size_t)d * 65 + lane], v);
    if (lane == 0) atomicAdd(&out[(size_t)d * 65 + 64], efeat[eidx]);
}

// ---------------------------------------------------------------------------

extern "C" void kernel_launch(void* const* d_in, const int* in_sizes, int n_in,
                              void* d_out, int out_size, void* d_ws, size_t ws_size,
                              hipStream_t stream) {
    const float* gemb  = (const float*)d_in[0];   // [N, 64]
    const float* efeat = (const float*)d_in[1];   // [E]
    const int*   src   = (const int*)d_in[2];     // [E]
    const int*   dst   = (const int*)d_in[3];     // [E]
    float*       out   = (float*)d_out;           // [N, 65]

    const int N  = in_sizes[0] / 64;
    const int E  = in_sizes[1];
    const int NB = (N + BNODES - 1) >> NB_SHIFT;

    auto aln = [](size_t x) { return (x + 63) & ~(size_t)63; };
    size_t off_counts = 0;                                    // [MAXNB]
    size_t off_goff   = aln(off_counts + (size_t)MAXNB * 4);
    size_t off_gcur   = aln(off_goff + (size_t)(NB + 1) * 4);
    size_t off_noff   = aln(off_gcur + (size_t)NB * 4);
    size_t off_gkey   = aln(off_noff + (size_t)(N + 1) * 4);
    size_t off_gef    = aln(off_gkey + (size_t)E * 4);
    size_t off_gsrc2  = aln(off_gef  + (size_t)E * 4);
    size_t off_hg     = aln(off_gsrc2 + (size_t)E * 4);
    size_t needed     = off_hg + (size_t)N * 64 * 2;

    if (N > (1 << SRC_BITS) || NB > MAXNB || ws_size < needed) {
        hipMemsetAsync(d_out, 0, (size_t)out_size * sizeof(float), stream);
        int blocks = (E + 3) / 4;
        atomic_fallback_kernel<<<blocks, 256, 0, stream>>>(gemb, efeat, src, dst, out, E);
        return;
    }

    char*   ws     = (char*)d_ws;
    int*    counts = (int*)(ws + off_counts);
    int*    goff   = (int*)(ws + off_goff);
    int*    gcur   = (int*)(ws + off_gcur);
    int*    noff   = (int*)(ws + off_noff);
    int*    gkey   = (int*)(ws + off_gkey);
    float*  gef    = (float*)(ws + off_gef);
    int*    gsrc2  = (int*)(ws + off_gsrc2);
    __half* hg     = (__half*)(ws + off_hg);

    hipMemsetAsync(counts, 0, (size_t)MAXNB * 4, stream);

    int n_emb    = N * 64;
    int c_blocks = (n_emb + BIN_T * 8 - 1) / (BIN_T * 8);
    int h_blocks = (E + BIN_S - 1) / BIN_S;
    convhist_kernel<<<c_blocks + h_blocks, BIN_T, 0, stream>>>(
        gemb, hg, n_emb, c_blocks, dst, counts, E, NB);

    scan_kernel<<<1, 512, 0, stream>>>(counts, goff, gcur, noff, NB, N);
    bin_kernel<<<h_blocks, BIN_T, 0, stream>>>(src, efeat, dst, gcur, gkey, gef, E);
    bsort_kernel<<<NB, 512, 0, stream>>>(gkey, gef, goff, gsrc2, noff, out, N);

    int g_blocks = (N + 3) / 4;
    gather_h_kernel<<<g_blocks, 256, 0, stream>>>(hg, gsrc2, noff, out, N);
}

// Round 17
// 92.998 us; speedup vs baseline: 1.0858x; 1.0858x over previous
//
#include <hip/hip_runtime.h>
#include <hip/hip_fp16.h>

// ---------------------------------------------------------------------------
// Round-17: r15 pipeline, gather switched to 2-nodes-per-wave.
//   memset(counts) ;
//   convhist (fp32->fp16 table conv + 391-bucket hist) ;
//   scan (1 block, shfl: bucket offsets; writes goff[NB], noff[N]) ;
//   bin (two-phase flush, 28KB LDS) ;
//   bsort (bucket window in LDS; node-sorted 4B srcs + noff; esum->out[:,64]) ;
//   gather2n (half-wave per node: lane loads uint=2xfp16, one 256B load
//             instruction covers TWO rows; independent 8/4/1 tails per half).
// Key: (dst & 255) << 17 | src   (needs N <= 2^17).
// ---------------------------------------------------------------------------

#define NB_SHIFT 8
#define BNODES   256          // nodes per bucket
#define SRC_BITS 17
#define SRC_MASK ((1 << SRC_BITS) - 1)
#define BIN_S    4096         // edges per bin/hist block
#define BIN_T    512
#define MAXNB    512
#define BS_CAP   3584         // bsort LDS window capacity (edges)

__global__ __launch_bounds__(BIN_T) void convhist_kernel(const float* __restrict__ g,
                                                         __half* __restrict__ h,
                                                         int n_emb, int c_blocks,
                                                         const int* __restrict__ dst,
                                                         int* __restrict__ counts,
                                                         int E, int NB) {
    __shared__ int cnt[MAXNB];
    int t = threadIdx.x;

    if (blockIdx.x < c_blocks) {
        int i = (blockIdx.x * BIN_T + t) * 8;
        if (i + 7 < n_emb) {
            float4 a = *(const float4*)(g + i);
            float4 b = *(const float4*)(g + i + 4);
            __half2 h0 = __floats2half2_rn(a.x, a.y);
            __half2 h1 = __floats2half2_rn(a.z, a.w);
            __half2 h2 = __floats2half2_rn(b.x, b.y);
            __half2 h3 = __floats2half2_rn(b.z, b.w);
            int4 o;
            o.x = *(int*)&h0; o.y = *(int*)&h1; o.z = *(int*)&h2; o.w = *(int*)&h3;
            *(int4*)(h + i) = o;
        } else {
            for (int k = i; k < n_emb; ++k) h[k] = __float2half(g[k]);
        }
        return;
    }

    int hb = blockIdx.x - c_blocks;
    cnt[t] = 0;
    __syncthreads();
    int e0 = hb * BIN_S + t * 8;
    if (e0 + 7 < E) {
        int4 a = *(const int4*)(dst + e0);
        int4 b = *(const int4*)(dst + e0 + 4);
        atomicAdd(&cnt[a.x >> NB_SHIFT], 1);
        atomicAdd(&cnt[a.y >> NB_SHIFT], 1);
        atomicAdd(&cnt[a.z >> NB_SHIFT], 1);
        atomicAdd(&cnt[a.w >> NB_SHIFT], 1);
        atomicAdd(&cnt[b.x >> NB_SHIFT], 1);
        atomicAdd(&cnt[b.y >> NB_SHIFT], 1);
        atomicAdd(&cnt[b.z >> NB_SHIFT], 1);
        atomicAdd(&cnt[b.w >> NB_SHIFT], 1);
    } else {
        for (int k = e0; k < E; ++k) atomicAdd(&cnt[dst[k] >> NB_SHIFT], 1);
    }
    __syncthreads();
    if (t < NB && cnt[t]) atomicAdd(&counts[t], cnt[t]);
}

__global__ __launch_bounds__(512) void scan_kernel(const int* __restrict__ counts,
                                                   int* __restrict__ goff,
                                                   int* __restrict__ gcur,
                                                   int* __restrict__ noff,
                                                   int NB, int N) {
    __shared__ int wsum[8];
    __shared__ int wbase[8];
    int t    = threadIdx.x;
    int lane = t & 63;
    int wv   = t >> 6;
    int v    = (t < NB) ? counts[t] : 0;
    int incl = v;
#pragma unroll
    for (int o = 1; o < 64; o <<= 1) {
        int u = __shfl_up(incl, o);
        if (lane >= o) incl += u;
    }
    if (lane == 63) wsum[wv] = incl;
    __syncthreads();
    if (t < 8) {
        int s = wsum[t];
        int inc = s;
#pragma unroll
        for (int o = 1; o < 8; o <<= 1) {
            int u = __shfl_up(inc, o);
            if (t >= o) inc += u;
        }
        wbase[t] = inc - s;
    }
    __syncthreads();
    int ex = wbase[wv] + (incl - v);
    if (t < NB) { goff[t] = ex; gcur[t] = ex; }
    if (t == 511) {
        int total = wbase[7] + incl;
        goff[NB] = total;
        noff[N]  = total;
    }
}

__global__ __launch_bounds__(BIN_T) void bin_kernel(const int* __restrict__ src,
                                                    const float* __restrict__ ef,
                                                    const int* __restrict__ dst,
                                                    int* __restrict__ gcur,
                                                    int* __restrict__ gkey,
                                                    float* __restrict__ gef, int E) {
    __shared__ int cnt[MAXNB];
    __shared__ int lbase[MAXNB];
    __shared__ int wsum[8];
    __shared__ int wbase[8];
    __shared__ int stage[BIN_S];            // 16 KB (keys, then ef bits)
    __shared__ unsigned short sbuck[BIN_S]; // 8 KB

    const int t    = threadIdx.x;
    const int lane = t & 63;
    const int wv   = t >> 6;

    cnt[t] = 0;
    __syncthreads();

    int e0 = blockIdx.x * BIN_S + t * 8;
    int dv[8], sv[8], bk[8], rk[8];
    float ev[8];

    if (e0 + 7 < E) {
        *(int4*)&dv[0]   = *(const int4*)(dst + e0);
        *(int4*)&dv[4]   = *(const int4*)(dst + e0 + 4);
        *(int4*)&sv[0]   = *(const int4*)(src + e0);
        *(int4*)&sv[4]   = *(const int4*)(src + e0 + 4);
        *(float4*)&ev[0] = *(const float4*)(ef + e0);
        *(float4*)&ev[4] = *(const float4*)(ef + e0 + 4);
#pragma unroll
        for (int k = 0; k < 8; ++k) {
            bk[k] = dv[k] >> NB_SHIFT;
            rk[k] = atomicAdd(&cnt[bk[k]], 1);
        }
    } else {
#pragma unroll
        for (int k = 0; k < 8; ++k) {
            if (e0 + k < E) {
                dv[k] = dst[e0 + k];
                sv[k] = src[e0 + k];
                ev[k] = ef[e0 + k];
                bk[k] = dv[k] >> NB_SHIFT;
                rk[k] = atomicAdd(&cnt[bk[k]], 1);
            } else {
                bk[k] = -1;
            }
        }
    }
    __syncthreads();

    int c = cnt[t];
    int incl = c;
#pragma unroll
    for (int o = 1; o < 64; o <<= 1) {
        int u = __shfl_up(incl, o);
        if (lane >= o) incl += u;
    }
    if (lane == 63) wsum[wv] = incl;
    __syncthreads();
    if (t < 8) {
        int s = wsum[t];
        int inc = s;
#pragma unroll
        for (int o = 1; o < 8; o <<= 1) {
            int u = __shfl_up(inc, o);
            if (t >= o) inc += u;
        }
        wbase[t] = inc - s;
    }
    __syncthreads();
    int lb = wbase[wv] + (incl - c);
    lbase[t] = lb;
    __syncthreads();

#pragma unroll
    for (int k = 0; k < 8; ++k) {
        if (bk[k] >= 0) {
            int pos = lbase[bk[k]] + rk[k];
            stage[pos] = ((dv[k] & (BNODES - 1)) << SRC_BITS) | sv[k];
            sbuck[pos] = (unsigned short)bk[k];
        }
    }
    cnt[t] = (c ? atomicAdd(&gcur[t], c) : 0) - lb;
    __syncthreads();

    int s_total = min(BIN_S, E - blockIdx.x * BIN_S);
    for (int i = t; i < s_total; i += BIN_T)
        gkey[cnt[sbuck[i]] + i] = stage[i];
    __syncthreads();

#pragma unroll
    for (int k = 0; k < 8; ++k) {
        if (bk[k] >= 0)
            stage[lbase[bk[k]] + rk[k]] = __float_as_int(ev[k]);
    }
    __syncthreads();
    for (int i = t; i < s_total; i += BIN_T)
        gef[cnt[sbuck[i]] + i] = __int_as_float(stage[i]);
}

__global__ __launch_bounds__(512) void bsort_kernel(const int* __restrict__ gkey,
                                                    const float* __restrict__ gef,
                                                    const int* __restrict__ goff,
                                                    int* __restrict__ gsrc2,
                                                    int* __restrict__ noff,
                                                    float* __restrict__ out,
                                                    int N) {
    __shared__ int   cnt[BNODES];
    __shared__ int   cur[BNODES];
    __shared__ float esum[BNODES];
    __shared__ int   wkey[BS_CAP];
    __shared__ float wef[BS_CAP];

    const int t  = threadIdx.x;
    const int b  = blockIdx.x;
    const int lo = goff[b];
    const int hi = goff[b + 1];
    const int csize  = hi - lo;
    const int staged = min(csize, BS_CAP);

    if (t < BNODES) { cnt[t] = 0; esum[t] = 0.f; }
    __syncthreads();

    for (int i = t; i < staged; i += 512) {
        int k   = gkey[lo + i];
        float e = gef[lo + i];
        wkey[i] = k;
        wef[i]  = e;
        atomicAdd(&cnt[k >> SRC_BITS], 1);
    }
    for (int i = BS_CAP + t; i < csize; i += 512)
        atomicAdd(&cnt[gkey[lo + i] >> SRC_BITS], 1);
    __syncthreads();

    if (t < 64) {
        int c0 = cnt[4 * t], c1 = cnt[4 * t + 1], c2 = cnt[4 * t + 2], c3 = cnt[4 * t + 3];
        int ts = c0 + c1 + c2 + c3;
        int inc = ts;
#pragma unroll
        for (int o = 1; o < 64; o <<= 1) {
            int u = __shfl_up(inc, o);
            if (t >= o) inc += u;
        }
        int ex = inc - ts;
        int b0 = lo + ex;
        int b1 = b0 + c0;
        int b2 = b1 + c1;
        int b3 = b2 + c2;
        cur[4 * t]     = b0;
        cur[4 * t + 1] = b1;
        cur[4 * t + 2] = b2;
        cur[4 * t + 3] = b3;
        int node = b * BNODES + 4 * t;
        if (node     < N) noff[node]     = b0;
        if (node + 1 < N) noff[node + 1] = b1;
        if (node + 2 < N) noff[node + 2] = b2;
        if (node + 3 < N) noff[node + 3] = b3;
    }
    __syncthreads();

    for (int i = t; i < staged; i += 512) {
        int k = wkey[i];
        int r = k >> SRC_BITS;
        int pos = atomicAdd(&cur[r], 1);
        gsrc2[pos] = k & SRC_MASK;
        atomicAdd(&esum[r], wef[i]);
    }
    for (int i = BS_CAP + t; i < csize; i += 512) {
        int k = gkey[lo + i];
        int r = k >> SRC_BITS;
        int pos = atomicAdd(&cur[r], 1);
        gsrc2[pos] = k & SRC_MASK;
        atomicAdd(&esum[r], gef[lo + i]);
    }
    __syncthreads();

    if (t < BNODES) {
        int node = b * BNODES + t;
        if (node < N) out[(size_t)node * 65 + 64] = esum[t];
    }
}

// Gather, 2 nodes per wave: half-wave h (lanes h*32..h*32+31) owns node
// 2*wid+h. Lane loads uint = 2 fp16 features; one wave-wide load instruction
// fetches TWO 128B rows. Each half runs its own 8/4/1 tail (exec-masked).
__global__ void gather_h2n_kernel(const __half* __restrict__ hg,
                                  const int* __restrict__ gs,
                                  const int* __restrict__ noff,
                                  float* __restrict__ out, int N) {
    int wid  = (blockIdx.x * blockDim.x + threadIdx.x) >> 6;
    int lane = threadIdx.x & 63;
    int half = lane >> 5;
    int l32  = lane & 31;
    int node = wid * 2 + half;
    if (node >= N) return;

    const unsigned int* __restrict__ hg32 = (const unsigned int*)hg;

    int beg = noff[node];
    int end = noff[node + 1];

    float ax0 = 0.f, ay0 = 0.f, ax1 = 0.f, ay1 = 0.f;
    float ax2 = 0.f, ay2 = 0.f, ax3 = 0.f, ay3 = 0.f;
    float ax4 = 0.f, ay4 = 0.f, ax5 = 0.f, ay5 = 0.f;
    float ax6 = 0.f, ay6 = 0.f, ax7 = 0.f, ay7 = 0.f;

    int j = beg;
    for (; j + 7 < end; j += 8) {
        int s0 = gs[j];     int s1 = gs[j + 1];
        int s2 = gs[j + 2]; int s3 = gs[j + 3];
        int s4 = gs[j + 4]; int s5 = gs[j + 5];
        int s6 = gs[j + 6]; int s7 = gs[j + 7];
        unsigned int u0 = hg32[(size_t)s0 * 32 + l32];
        unsigned int u1 = hg32[(size_t)s1 * 32 + l32];
        unsigned int u2 = hg32[(size_t)s2 * 32 + l32];
        unsigned int u3 = hg32[(size_t)s3 * 32 + l32];
        unsigned int u4 = hg32[(size_t)s4 * 32 + l32];
        unsigned int u5 = hg32[(size_t)s5 * 32 + l32];
        unsigned int u6 = hg32[(size_t)s6 * 32 + l32];
        unsigned int u7 = hg32[(size_t)s7 * 32 + l32];
        __half2 h0 = *(__half2*)&u0; ax0 += __half2float(h0.x); ay0 += __half2float(h0.y);
        __half2 h1 = *(__half2*)&u1; ax1 += __half2float(h1.x); ay1 += __half2float(h1.y);
        __half2 h2 = *(__half2*)&u2; ax2 += __half2float(h2.x); ay2 += __half2float(h2.y);
        __half2 h3 = *(__half2*)&u3; ax3 += __half2float(h3.x); ay3 += __half2float(h3.y);
        __half2 h4 = *(__half2*)&u4; ax4 += __half2float(h4.x); ay4 += __half2float(h4.y);
        __half2 h5 = *(__half2*)&u5; ax5 += __half2float(h5.x); ay5 += __half2float(h5.y);
        __half2 h6 = *(__half2*)&u6; ax6 += __half2float(h6.x); ay6 += __half2float(h6.y);
        __half2 h7 = *(__half2*)&u7; ax7 += __half2float(h7.x); ay7 += __half2float(h7.y);
    }
    for (; j + 3 < end; j += 4) {
        int s0 = gs[j];     int s1 = gs[j + 1];
        int s2 = gs[j + 2]; int s3 = gs[j + 3];
        unsigned int u0 = hg32[(size_t)s0 * 32 + l32];
        unsigned int u1 = hg32[(size_t)s1 * 32 + l32];
        unsigned int u2 = hg32[(size_t)s2 * 32 + l32];
        unsigned int u3 = hg32[(size_t)s3 * 32 + l32];
        __half2 h0 = *(__half2*)&u0; ax0 += __half2float(h0.x); ay0 += __half2float(h0.y);
        __half2 h1 = *(__half2*)&u1; ax1 += __half2float(h1.x); ay1 += __half2float(h1.y);
        __half2 h2 = *(__half2*)&u2; ax2 += __half2float(h2.x); ay2 += __half2float(h2.y);
        __half2 h3 = *(__half2*)&u3; ax3 += __half2float(h3.x); ay3 += __half2float(h3.y);
    }
    for (; j < end; ++j) {
        unsigned int u = hg32[(size_t)gs[j] * 32 + l32];
        __half2 h = *(__half2*)&u;
        ax0 += __half2float(h.x);
        ay0 += __half2float(h.y);
    }

    float ax = ((ax0 + ax1) + (ax2 + ax3)) + ((ax4 + ax5) + (ax6 + ax7));
    float ay = ((ay0 + ay1) + (ay2 + ay3)) + ((ay4 + ay5) + (ay6 + ay7));

    size_t base = (size_t)node * 65 + 2 * l32;
    out[base]     = ax;
    out[base + 1] = ay;
}

// ---------------------- fallback (always correct) --------------------------

__global__ void atomic_fallback_kernel(const float* __restrict__ gemb,
                                       const float* __restrict__ efeat,
                                       const int* __restrict__ src,
                                       const int* __restrict__ dst,
                                       float* __restrict__ out, int E) {
    int eidx = blockIdx.x * 4 + (threadIdx.x >> 6);
    int lane = threadIdx.x & 63;
    if (eidx >= E) return;
    int s = src[eidx];
    int d = dst[eidx];
    float v = gemb[(size_t)s * 64 + lane];
    atomicAdd(&out[(size_t)d * 65 + lane], v);
    if (lane == 0) atomicAdd(&out[(size_t)d * 65 + 64], efeat[eidx]);
}

// ---------------------------------------------------------------------------

extern "C" void kernel_launch(void* const* d_in, const int* in_sizes, int n_in,
                              void* d_out, int out_size, void* d_ws, size_t ws_size,
                              hipStream_t stream) {
    const float* gemb  = (const float*)d_in[0];   // [N, 64]
    const float* efeat = (const float*)d_in[1];   // [E]
    const int*   src   = (const int*)d_in[2];     // [E]
    const int*   dst   = (const int*)d_in[3];     // [E]
    float*       out   = (float*)d_out;           // [N, 65]

    const int N  = in_sizes[0] / 64;
    const int E  = in_sizes[1];
    const int NB = (N + BNODES - 1) >> NB_SHIFT;

    auto aln = [](size_t x) { return (x + 63) & ~(size_t)63; };
    size_t off_counts = 0;
    size_t off_goff   = aln(off_counts + (size_t)MAXNB * 4);
    size_t off_gcur   = aln(off_goff + (size_t)(NB + 1) * 4);
    size_t off_noff   = aln(off_gcur + (size_t)NB * 4);
    size_t off_gkey   = aln(off_noff + (size_t)(N + 1) * 4);
    size_t off_gef    = aln(off_gkey + (size_t)E * 4);
    size_t off_gsrc2  = aln(off_gef  + (size_t)E * 4);
    size_t off_hg     = aln(off_gsrc2 + (size_t)E * 4);
    size_t needed     = off_hg + (size_t)N * 64 * 2;

    if (N > (1 << SRC_BITS) || NB > MAXNB || ws_size < needed) {
        hipMemsetAsync(d_out, 0, (size_t)out_size * sizeof(float), stream);
        int blocks = (E + 3) / 4;
        atomic_fallback_kernel<<<blocks, 256, 0, stream>>>(gemb, efeat, src, dst, out, E);
        return;
    }

    char*   ws     = (char*)d_ws;
    int*    counts = (int*)(ws + off_counts);
    int*    goff   = (int*)(ws + off_goff);
    int*    gcur   = (int*)(ws + off_gcur);
    int*    noff   = (int*)(ws + off_noff);
    int*    gkey   = (int*)(ws + off_gkey);
    float*  gef    = (float*)(ws + off_gef);
    int*    gsrc2  = (int*)(ws + off_gsrc2);
    __half* hg     = (__half*)(ws + off_hg);

    hipMemsetAsync(counts, 0, (size_t)MAXNB * 4, stream);

    int n_emb    = N * 64;
    int c_blocks = (n_emb + BIN_T * 8 - 1) / (BIN_T * 8);
    int h_blocks = (E + BIN_S - 1) / BIN_S;
    convhist_kernel<<<c_blocks + h_blocks, BIN_T, 0, stream>>>(
        gemb, hg, n_emb, c_blocks, dst, counts, E, NB);

    scan_kernel<<<1, 512, 0, stream>>>(counts, goff, gcur, noff, NB, N);
    bin_kernel<<<h_blocks, BIN_T, 0, stream>>>(src, efeat, dst, gcur, gkey, gef, E);
    bsort_kernel<<<NB, 512, 0, stream>>>(gkey, gef, goff, gsrc2, noff, out, N);

    // 2 nodes per wave, 4 waves per block -> 8 nodes per block
    int g_blocks = (N + 7) / 8;
    gather_h2n_kernel<<<g_blocks, 256, 0, stream>>>(hg, gsrc2, noff, out, N);
}

// Round 18
// 91.608 us; speedup vs baseline: 1.1022x; 1.0152x over previous
//
#include <hip/hip_runtime.h>
#include <hip/hip_fp16.h>

// ---------------------------------------------------------------------------
// Round-18: r17 pipeline, gather pushed to 4-nodes-per-wave.
//   memset(counts) ;
//   convhist (fp32->fp16 table conv + 391-bucket hist) ;
//   scan (1 block, shfl: bucket offsets; writes goff[NB], noff[N]) ;
//   bin (two-phase flush, 28KB LDS) ;
//   bsort (bucket window in LDS; node-sorted 4B srcs + noff; esum->out[:,64]) ;
//   gather4n (quarter-wave per node: lane loads uint2 = 4 fp16; one wave-wide
//             load instruction covers FOUR 128B rows; per-node 8/4/1 tails).
// Key: (dst & 255) << 17 | src   (needs N <= 2^17).
// ---------------------------------------------------------------------------

#define NB_SHIFT 8
#define BNODES   256          // nodes per bucket
#define SRC_BITS 17
#define SRC_MASK ((1 << SRC_BITS) - 1)
#define BIN_S    4096         // edges per bin/hist block
#define BIN_T    512
#define MAXNB    512
#define BS_CAP   3584         // bsort LDS window capacity (edges)

__global__ __launch_bounds__(BIN_T) void convhist_kernel(const float* __restrict__ g,
                                                         __half* __restrict__ h,
                                                         int n_emb, int c_blocks,
                                                         const int* __restrict__ dst,
                                                         int* __restrict__ counts,
                                                         int E, int NB) {
    __shared__ int cnt[MAXNB];
    int t = threadIdx.x;

    if (blockIdx.x < c_blocks) {
        int i = (blockIdx.x * BIN_T + t) * 8;
        if (i + 7 < n_emb) {
            float4 a = *(const float4*)(g + i);
            float4 b = *(const float4*)(g + i + 4);
            __half2 h0 = __floats2half2_rn(a.x, a.y);
            __half2 h1 = __floats2half2_rn(a.z, a.w);
            __half2 h2 = __floats2half2_rn(b.x, b.y);
            __half2 h3 = __floats2half2_rn(b.z, b.w);
            int4 o;
            o.x = *(int*)&h0; o.y = *(int*)&h1; o.z = *(int*)&h2; o.w = *(int*)&h3;
            *(int4*)(h + i) = o;
        } else {
            for (int k = i; k < n_emb; ++k) h[k] = __float2half(g[k]);
        }
        return;
    }

    int hb = blockIdx.x - c_blocks;
    cnt[t] = 0;
    __syncthreads();
    int e0 = hb * BIN_S + t * 8;
    if (e0 + 7 < E) {
        int4 a = *(const int4*)(dst + e0);
        int4 b = *(const int4*)(dst + e0 + 4);
        atomicAdd(&cnt[a.x >> NB_SHIFT], 1);
        atomicAdd(&cnt[a.y >> NB_SHIFT], 1);
        atomicAdd(&cnt[a.z >> NB_SHIFT], 1);
        atomicAdd(&cnt[a.w >> NB_SHIFT], 1);
        atomicAdd(&cnt[b.x >> NB_SHIFT], 1);
        atomicAdd(&cnt[b.y >> NB_SHIFT], 1);
        atomicAdd(&cnt[b.z >> NB_SHIFT], 1);
        atomicAdd(&cnt[b.w >> NB_SHIFT], 1);
    } else {
        for (int k = e0; k < E; ++k) atomicAdd(&cnt[dst[k] >> NB_SHIFT], 1);
    }
    __syncthreads();
    if (t < NB && cnt[t]) atomicAdd(&counts[t], cnt[t]);
}

__global__ __launch_bounds__(512) void scan_kernel(const int* __restrict__ counts,
                                                   int* __restrict__ goff,
                                                   int* __restrict__ gcur,
                                                   int* __restrict__ noff,
                                                   int NB, int N) {
    __shared__ int wsum[8];
    __shared__ int wbase[8];
    int t    = threadIdx.x;
    int lane = t & 63;
    int wv   = t >> 6;
    int v    = (t < NB) ? counts[t] : 0;
    int incl = v;
#pragma unroll
    for (int o = 1; o < 64; o <<= 1) {
        int u = __shfl_up(incl, o);
        if (lane >= o) incl += u;
    }
    if (lane == 63) wsum[wv] = incl;
    __syncthreads();
    if (t < 8) {
        int s = wsum[t];
        int inc = s;
#pragma unroll
        for (int o = 1; o < 8; o <<= 1) {
            int u = __shfl_up(inc, o);
            if (t >= o) inc += u;
        }
        wbase[t] = inc - s;
    }
    __syncthreads();
    int ex = wbase[wv] + (incl - v);
    if (t < NB) { goff[t] = ex; gcur[t] = ex; }
    if (t == 511) {
        int total = wbase[7] + incl;
        goff[NB] = total;
        noff[N]  = total;
    }
}

__global__ __launch_bounds__(BIN_T) void bin_kernel(const int* __restrict__ src,
                                                    const float* __restrict__ ef,
                                                    const int* __restrict__ dst,
                                                    int* __restrict__ gcur,
                                                    int* __restrict__ gkey,
                                                    float* __restrict__ gef, int E) {
    __shared__ int cnt[MAXNB];
    __shared__ int lbase[MAXNB];
    __shared__ int wsum[8];
    __shared__ int wbase[8];
    __shared__ int stage[BIN_S];            // 16 KB (keys, then ef bits)
    __shared__ unsigned short sbuck[BIN_S]; // 8 KB

    const int t    = threadIdx.x;
    const int lane = t & 63;
    const int wv   = t >> 6;

    cnt[t] = 0;
    __syncthreads();

    int e0 = blockIdx.x * BIN_S + t * 8;
    int dv[8], sv[8], bk[8], rk[8];
    float ev[8];

    if (e0 + 7 < E) {
        *(int4*)&dv[0]   = *(const int4*)(dst + e0);
        *(int4*)&dv[4]   = *(const int4*)(dst + e0 + 4);
        *(int4*)&sv[0]   = *(const int4*)(src + e0);
        *(int4*)&sv[4]   = *(const int4*)(src + e0 + 4);
        *(float4*)&ev[0] = *(const float4*)(ef + e0);
        *(float4*)&ev[4] = *(const float4*)(ef + e0 + 4);
#pragma unroll
        for (int k = 0; k < 8; ++k) {
            bk[k] = dv[k] >> NB_SHIFT;
            rk[k] = atomicAdd(&cnt[bk[k]], 1);
        }
    } else {
#pragma unroll
        for (int k = 0; k < 8; ++k) {
            if (e0 + k < E) {
                dv[k] = dst[e0 + k];
                sv[k] = src[e0 + k];
                ev[k] = ef[e0 + k];
                bk[k] = dv[k] >> NB_SHIFT;
                rk[k] = atomicAdd(&cnt[bk[k]], 1);
            } else {
                bk[k] = -1;
            }
        }
    }
    __syncthreads();

    int c = cnt[t];
    int incl = c;
#pragma unroll
    for (int o = 1; o < 64; o <<= 1) {
        int u = __shfl_up(incl, o);
        if (lane >= o) incl += u;
    }
    if (lane == 63) wsum[wv] = incl;
    __syncthreads();
    if (t < 8) {
        int s = wsum[t];
        int inc = s;
#pragma unroll
        for (int o = 1; o < 8; o <<= 1) {
            int u = __shfl_up(inc, o);
            if (t >= o) inc += u;
        }
        wbase[t] = inc - s;
    }
    __syncthreads();
    int lb = wbase[wv] + (incl - c);
    lbase[t] = lb;
    __syncthreads();

#pragma unroll
    for (int k = 0; k < 8; ++k) {
        if (bk[k] >= 0) {
            int pos = lbase[bk[k]] + rk[k];
            stage[pos] = ((dv[k] & (BNODES - 1)) << SRC_BITS) | sv[k];
            sbuck[pos] = (unsigned short)bk[k];
        }
    }
    cnt[t] = (c ? atomicAdd(&gcur[t], c) : 0) - lb;
    __syncthreads();

    int s_total = min(BIN_S, E - blockIdx.x * BIN_S);
    for (int i = t; i < s_total; i += BIN_T)
        gkey[cnt[sbuck[i]] + i] = stage[i];
    __syncthreads();

#pragma unroll
    for (int k = 0; k < 8; ++k) {
        if (bk[k] >= 0)
            stage[lbase[bk[k]] + rk[k]] = __float_as_int(ev[k]);
    }
    __syncthreads();
    for (int i = t; i < s_total; i += BIN_T)
        gef[cnt[sbuck[i]] + i] = __int_as_float(stage[i]);
}

__global__ __launch_bounds__(512) void bsort_kernel(const int* __restrict__ gkey,
                                                    const float* __restrict__ gef,
                                                    const int* __restrict__ goff,
                                                    int* __restrict__ gsrc2,
                                                    int* __restrict__ noff,
                                                    float* __restrict__ out,
                                                    int N) {
    __shared__ int   cnt[BNODES];
    __shared__ int   cur[BNODES];
    __shared__ float esum[BNODES];
    __shared__ int   wkey[BS_CAP];
    __shared__ float wef[BS_CAP];

    const int t  = threadIdx.x;
    const int b  = blockIdx.x;
    const int lo = goff[b];
    const int hi = goff[b + 1];
    const int csize  = hi - lo;
    const int staged = min(csize, BS_CAP);

    if (t < BNODES) { cnt[t] = 0; esum[t] = 0.f; }
    __syncthreads();

    for (int i = t; i < staged; i += 512) {
        int k   = gkey[lo + i];
        float e = gef[lo + i];
        wkey[i] = k;
        wef[i]  = e;
        atomicAdd(&cnt[k >> SRC_BITS], 1);
    }
    for (int i = BS_CAP + t; i < csize; i += 512)
        atomicAdd(&cnt[gkey[lo + i] >> SRC_BITS], 1);
    __syncthreads();

    if (t < 64) {
        int c0 = cnt[4 * t], c1 = cnt[4 * t + 1], c2 = cnt[4 * t + 2], c3 = cnt[4 * t + 3];
        int ts = c0 + c1 + c2 + c3;
        int inc = ts;
#pragma unroll
        for (int o = 1; o < 64; o <<= 1) {
            int u = __shfl_up(inc, o);
            if (t >= o) inc += u;
        }
        int ex = inc - ts;
        int b0 = lo + ex;
        int b1 = b0 + c0;
        int b2 = b1 + c1;
        int b3 = b2 + c2;
        cur[4 * t]     = b0;
        cur[4 * t + 1] = b1;
        cur[4 * t + 2] = b2;
        cur[4 * t + 3] = b3;
        int node = b * BNODES + 4 * t;
        if (node     < N) noff[node]     = b0;
        if (node + 1 < N) noff[node + 1] = b1;
        if (node + 2 < N) noff[node + 2] = b2;
        if (node + 3 < N) noff[node + 3] = b3;
    }
    __syncthreads();

    for (int i = t; i < staged; i += 512) {
        int k = wkey[i];
        int r = k >> SRC_BITS;
        int pos = atomicAdd(&cur[r], 1);
        gsrc2[pos] = k & SRC_MASK;
        atomicAdd(&esum[r], wef[i]);
    }
    for (int i = BS_CAP + t; i < csize; i += 512) {
        int k = gkey[lo + i];
        int r = k >> SRC_BITS;
        int pos = atomicAdd(&cur[r], 1);
        gsrc2[pos] = k & SRC_MASK;
        atomicAdd(&esum[r], gef[lo + i]);
    }
    __syncthreads();

    if (t < BNODES) {
        int node = b * BNODES + t;
        if (node < N) out[(size_t)node * 65 + 64] = esum[t];
    }
}

// Gather, 4 nodes per wave: quarter-wave q (lanes q*16..q*16+15) owns node
// 4*wid+q. Lane loads uint2 = 4 fp16 features; one wave-wide load instruction
// fetches FOUR 128B rows. Accumulators rotate across 4 named sets for ILP.
__global__ void gather_h4n_kernel(const __half* __restrict__ hg,
                                  const int* __restrict__ gs,
                                  const int* __restrict__ noff,
                                  float* __restrict__ out, int N) {
    int wid  = (blockIdx.x * blockDim.x + threadIdx.x) >> 6;
    int lane = threadIdx.x & 63;
    int q    = lane >> 4;     // quarter 0..3
    int l16  = lane & 15;     // feature quad index (features 4*l16 .. 4*l16+3)
    int node = wid * 4 + q;
    if (node >= N) return;

    const uint2* __restrict__ hg64 = (const uint2*)hg;   // 8B = 4 fp16

    int beg = noff[node];
    int end = noff[node + 1];

    float s0x = 0.f, s0y = 0.f, s0z = 0.f, s0w = 0.f;
    float s1x = 0.f, s1y = 0.f, s1z = 0.f, s1w = 0.f;
    float s2x = 0.f, s2y = 0.f, s2z = 0.f, s2w = 0.f;
    float s3x = 0.f, s3y = 0.f, s3z = 0.f, s3w = 0.f;

    int j = beg;
    for (; j + 7 < end; j += 8) {
        int a0 = gs[j];     int a1 = gs[j + 1];
        int a2 = gs[j + 2]; int a3 = gs[j + 3];
        int a4 = gs[j + 4]; int a5 = gs[j + 5];
        int a6 = gs[j + 6]; int a7 = gs[j + 7];
        uint2 u0 = hg64[(size_t)a0 * 16 + l16];
        uint2 u1 = hg64[(size_t)a1 * 16 + l16];
        uint2 u2 = hg64[(size_t)a2 * 16 + l16];
        uint2 u3 = hg64[(size_t)a3 * 16 + l16];
        uint2 u4 = hg64[(size_t)a4 * 16 + l16];
        uint2 u5 = hg64[(size_t)a5 * 16 + l16];
        uint2 u6 = hg64[(size_t)a6 * 16 + l16];
        uint2 u7 = hg64[(size_t)a7 * 16 + l16];
        __half2 p, r;
        p = *(__half2*)&u0.x; r = *(__half2*)&u0.y;
        s0x += __half2float(p.x); s0y += __half2float(p.y);
        s0z += __half2float(r.x); s0w += __half2float(r.y);
        p = *(__half2*)&u1.x; r = *(__half2*)&u1.y;
        s1x += __half2float(p.x); s1y += __half2float(p.y);
        s1z += __half2float(r.x); s1w += __half2float(r.y);
        p = *(__half2*)&u2.x; r = *(__half2*)&u2.y;
        s2x += __half2float(p.x); s2y += __half2float(p.y);
        s2z += __half2float(r.x); s2w += __half2float(r.y);
        p = *(__half2*)&u3.x; r = *(__half2*)&u3.y;
        s3x += __half2float(p.x); s3y += __half2float(p.y);
        s3z += __half2float(r.x); s3w += __half2float(r.y);
        p = *(__half2*)&u4.x; r = *(__half2*)&u4.y;
        s0x += __half2float(p.x); s0y += __half2float(p.y);
        s0z += __half2float(r.x); s0w += __half2float(r.y);
        p = *(__half2*)&u5.x; r = *(__half2*)&u5.y;
        s1x += __half2float(p.x); s1y += __half2float(p.y);
        s1z += __half2float(r.x); s1w += __half2float(r.y);
        p = *(__half2*)&u6.x; r = *(__half2*)&u6.y;
        s2x += __half2float(p.x); s2y += __half2float(p.y);
        s2z += __half2float(r.x); s2w += __half2float(r.y);
        p = *(__half2*)&u7.x; r = *(__half2*)&u7.y;
        s3x += __half2float(p.x); s3y += __half2float(p.y);
        s3z += __half2float(r.x); s3w += __half2float(r.y);
    }
    for (; j + 3 < end; j += 4) {
        int a0 = gs[j];     int a1 = gs[j + 1];
        int a2 = gs[j + 2]; int a3 = gs[j + 3];
        uint2 u0 = hg64[(size_t)a0 * 16 + l16];
        uint2 u1 = hg64[(size_t)a1 * 16 + l16];
        uint2 u2 = hg64[(size_t)a2 * 16 + l16];
        uint2 u3 = hg64[(size_t)a3 * 16 + l16];
        __half2 p, r;
        p = *(__half2*)&u0.x; r = *(__half2*)&u0.y;
        s0x += __half2float(p.x); s0y += __half2float(p.y);
        s0z += __half2float(r.x); s0w += __half2float(r.y);
        p = *(__half2*)&u1.x; r = *(__half2*)&u1.y;
        s1x += __half2float(p.x); s1y += __half2float(p.y);
        s1z += __half2float(r.x); s1w += __half2float(r.y);
        p = *(__half2*)&u2.x; r = *(__half2*)&u2.y;
        s2x += __half2float(p.x); s2y += __half2float(p.y);
        s2z += __half2float(r.x); s2w += __half2float(r.y);
        p = *(__half2*)&u3.x; r = *(__half2*)&u3.y;
        s3x += __half2float(p.x); s3y += __half2float(p.y);
        s3z += __half2float(r.x); s3w += __half2float(r.y);
    }
    for (; j < end; ++j) {
        uint2 u = hg64[(size_t)gs[j] * 16 + l16];
        __half2 p = *(__half2*)&u.x;
        __half2 r = *(__half2*)&u.y;
        s0x += __half2float(p.x); s0y += __half2float(p.y);
        s0z += __half2float(r.x); s0w += __half2float(r.y);
    }

    float x = (s0x + s1x) + (s2x + s3x);
    float y = (s0y + s1y) + (s2y + s3y);
    float z = (s0z + s1z) + (s2z + s3z);
    float w = (s0w + s1w) + (s2w + s3w);

    size_t base = (size_t)node * 65 + 4 * l16;
    out[base]     = x;
    out[base + 1] = y;
    out[base + 2] = z;
    out[base + 3] = w;
}

// ---------------------- fallback (always correct) --------------------------

__global__ void atomic_fallback_kernel(const float* __restrict__ gemb,
                                       const float* __restrict__ efeat,
                                       const int* __restrict__ src,
                                       const int* __restrict__ dst,
                                       float* __restrict__ out, int E) {
    int eidx = blockIdx.x * 4 + (threadIdx.x >> 6);
    int lane = threadIdx.x & 63;
    if (eidx >= E) return;
    int s = src[eidx];
    int d = dst[eidx];
    float v = gemb[(size_t)s * 64 + lane];
    atomicAdd(&out[(size_t)d * 65 + lane], v);
    if (lane == 0) atomicAdd(&out[(size_t)d * 65 + 64], efeat[eidx]);
}

// ---------------------------------------------------------------------------

extern "C" void kernel_launch(void* const* d_in, const int* in_sizes, int n_in,
                              void* d_out, int out_size, void* d_ws, size_t ws_size,
                              hipStream_t stream) {
    const float* gemb  = (const float*)d_in[0];   // [N, 64]
    const float* efeat = (const float*)d_in[1];   // [E]
    const int*   src   = (const int*)d_in[2];     // [E]
    const int*   dst   = (const int*)d_in[3];     // [E]
    float*       out   = (float*)d_out;           // [N, 65]

    const int N  = in_sizes[0] / 64;
    const int E  = in_sizes[1];
    const int NB = (N + BNODES - 1) >> NB_SHIFT;

    auto aln = [](size_t x) { return (x + 63) & ~(size_t)63; };
    size_t off_counts = 0;
    size_t off_goff   = aln(off_counts + (size_t)MAXNB * 4);
    size_t off_gcur   = aln(off_goff + (size_t)(NB + 1) * 4);
    size_t off_noff   = aln(off_gcur + (size_t)NB * 4);
    size_t off_gkey   = aln(off_noff + (size_t)(N + 1) * 4);
    size_t off_gef    = aln(off_gkey + (size_t)E * 4);
    size_t off_gsrc2  = aln(off_gef  + (size_t)E * 4);
    size_t off_hg     = aln(off_gsrc2 + (size_t)E * 4);
    size_t needed     = off_hg + (size_t)N * 64 * 2;

    if (N > (1 << SRC_BITS) || NB > MAXNB || ws_size < needed) {
        hipMemsetAsync(d_out, 0, (size_t)out_size * sizeof(float), stream);
        int blocks = (E + 3) / 4;
        atomic_fallback_kernel<<<blocks, 256, 0, stream>>>(gemb, efeat, src, dst, out, E);
        return;
    }

    char*   ws     = (char*)d_ws;
    int*    counts = (int*)(ws + off_counts);
    int*    goff   = (int*)(ws + off_goff);
    int*    gcur   = (int*)(ws + off_gcur);
    int*    noff   = (int*)(ws + off_noff);
    int*    gkey   = (int*)(ws + off_gkey);
    float*  gef    = (float*)(ws + off_gef);
    int*    gsrc2  = (int*)(ws + off_gsrc2);
    __half* hg     = (__half*)(ws + off_hg);

    hipMemsetAsync(counts, 0, (size_t)MAXNB * 4, stream);

    int n_emb    = N * 64;
    int c_blocks = (n_emb + BIN_T * 8 - 1) / (BIN_T * 8);
    int h_blocks = (E + BIN_S - 1) / BIN_S;
    convhist_kernel<<<c_blocks + h_blocks, BIN_T, 0, stream>>>(
        gemb, hg, n_emb, c_blocks, dst, counts, E, NB);

    scan_kernel<<<1, 512, 0, stream>>>(counts, goff, gcur, noff, NB, N);
    bin_kernel<<<h_blocks, BIN_T, 0, stream>>>(src, efeat, dst, gcur, gkey, gef, E);
    bsort_kernel<<<NB, 512, 0, stream>>>(gkey, gef, goff, gsrc2, noff, out, N);

    // 4 nodes per wave, 4 waves per block -> 16 nodes per block
    int g_blocks = (N + 15) / 16;
    gather_h4n_kernel<<<g_blocks, 256, 0, stream>>>(hg, gsrc2, noff, out, N);
}